// Round 1
// baseline (2300.217 us; speedup 1.0000x reference)
//
#include <hip/hip_runtime.h>

typedef unsigned int u32;
typedef __attribute__((ext_vector_type(8))) short short8;
typedef __attribute__((ext_vector_type(4))) short short4v;
typedef __attribute__((ext_vector_type(4))) float f32x4;

__device__ __forceinline__ float lrelu(float x){ return x > 0.f ? x : 0.2f*x; }

// float atomic max via sign-split (dest init -inf)
__device__ __forceinline__ void atomicMaxF(float* a, float v){
  if (__float_as_int(v) >= 0) atomicMax((int*)a, __float_as_int(v));
  else                        atomicMin((u32*)a, __float_as_uint(v));
}

__global__ void init_ws(float* __restrict__ nf1, float* __restrict__ nf2, int n32){
  int i = blockIdx.x*blockDim.x + threadIdx.x;
  int st = gridDim.x*blockDim.x;
  for (; i < n32; i += st){ nf1[i] = 0.f; nf2[i] = -__builtin_inff(); }
}

// RNE split: x = bf16(hi) + bf16(lo) + O(2^-18 x).
struct HL { short hi, lo; };
__device__ __forceinline__ HL split1(float x){
  u32 u = __float_as_uint(x);
  u32 r = u + 0x7FFFu + ((u >> 16) & 1u);
  float l = x - __uint_as_float(r & 0xFFFF0000u);
  HL o; o.hi = (short)(r >> 16); o.lo = (short)(__float_as_uint(l) >> 16);
  return o;
}

// one-time gather of a B fragment (W row-major [K][Nout], f32) with zero-fill OOB
__device__ __forceinline__ void gatherB(const float* __restrict__ W, int K, int Nout,
                                        int kbase, int n, short8& hi, short8& lo){
  #pragma unroll
  for (int j = 0; j < 8; ++j){
    int k = kbase + j;
    float w = (k < K && n < Nout) ? W[(size_t)k * Nout + n] : 0.f;
    HL s = split1(w); hi[j] = s.hi; lo[j] = s.lo;
  }
}

// 3-product accurate bf16 MFMA: D += Ah*Bh + Al*Bh + Ah*Bl
__device__ __forceinline__ f32x4 mfma3(short8 ah, short8 al, short8 bh, short8 bl, f32x4 c){
  c = __builtin_amdgcn_mfma_f32_16x16x32_bf16(ah, bh, c, 0, 0, 0);
  c = __builtin_amdgcn_mfma_f32_16x16x32_bf16(al, bh, c, 0, 0, 0);
  c = __builtin_amdgcn_mfma_f32_16x16x32_bf16(ah, bl, c, 0, 0, 0);
  return c;
}

// pre-split stores: split once at producer, consumers ds_read_b128 hi/lo planes directly
__device__ __forceinline__ void sstore1(short* hp, short* lp, int idx, float x){
  HL s = split1(x); hp[idx] = s.hi; lp[idx] = s.lo;
}
__device__ __forceinline__ void sstore4(short* hp, short* lp, int idx, f32x4 v){
  short4v h, l;
  #pragma unroll
  for (int j = 0; j < 4; ++j){ HL s = split1(v[j]); h[j] = s.hi; l[j] = s.lo; }
  *(short4v*)(hp + idx) = h;
  *(short4v*)(lp + idx) = l;
}

// ---- edge kernel LDS geometry (all strides in shorts) ----
// stride/4 mod 8 == 4 (odd multiple of 4 dwords) -> uniform bank spread for b128 row reads;
// strides are multiples of 8 shorts so rows stay 16B-aligned for ds_read_b128.
#define XS   168            // X rows: 144 real cols + zero pad to K=160 (L1 reads kc=4)
#define H1S  72             // 64-col buffers
#define H2S  136            // 128-col buffer
#define XPL  (64*XS)        // 10752 shorts per X plane
#define H1PL (64*H1S)       // 4608 shorts per H1 plane
// short offsets: Xh[2]@0, Xl[2]@21504, H1h[2]@43008, H1l[2]@52224, H2h@61440, H2l@70144, dstI@78848
#define LDS_SHORTS 79104
#define LDS_BYTES  (LDS_SHORTS*2)   // 158208 B -> 1 block/CU (already reg-limited to that)

// -------- edge kernel: 64 edges per block-tile, 8 waves, weights in regs, 3 barriers/tile --------
// MLP_msg 144->64->128->64->65; gate=sigmoid(col0); cols1..32 *g -> sum, 33..64 *g -> max
__global__ __launch_bounds__(512, 2) void edge_mfma(
    const float* __restrict__ nf, const float* __restrict__ ef,
    const int* __restrict__ src, const int* __restrict__ dst,
    const float* __restrict__ Wm1, const float* __restrict__ bm1,
    const float* __restrict__ Wm2, const float* __restrict__ bm2,
    const float* __restrict__ Wm3, const float* __restrict__ bm3,
    const float* __restrict__ Wm4, const float* __restrict__ bm4,
    float* __restrict__ nf1, float* __restrict__ nf2, int E)
{
  extern __shared__ short smem[];
  short* Xh  = smem;            // [2][XPL]
  short* Xl  = smem + 21504;    // [2][XPL]
  short* H1h = smem + 43008;    // [2][H1PL]
  short* H1l = smem + 52224;    // [2][H1PL]
  short* H2h = smem + 61440;    // [64*H2S]
  short* H2l = smem + 70144;    // [64*H2S]
  int*  dstI = (int*)(smem + 78848);  // [2][64]

  // zero all LDS once: X pad cols 144..159 must be 0 for the kc=4 MFMA (never rewritten);
  // uninit LDS can hold NaN and 0*NaN = NaN in MFMA.
  {
    float* z = (float*)smem;
    for (int i = threadIdx.x; i < LDS_SHORTS/2; i += blockDim.x) z[i] = 0.f;
  }

  const int lane = threadIdx.x & 63, wv = threadIdx.x >> 6;
  const int nl = lane & 15, quad = lane >> 4;
  const int m1 = wv >> 2, nb1 = wv & 3;   // (m-half, n-block)
  const int slot = wv*4 + quad;           // 0..31, stages rows slot*2, slot*2+1

  // ---- loop-invariant B fragments (hi/lo bf16) in registers ----
  short8 B1h[5], B1l[5];
  #pragma unroll
  for (int kc = 0; kc < 5; ++kc) gatherB(Wm1, 144, 64,  kc*32 + quad*8, nb1*16 + nl, B1h[kc], B1l[kc]);
  short8 B2h[2][2], B2l[2][2];
  #pragma unroll
  for (int i = 0; i < 2; ++i)
    #pragma unroll
    for (int kc = 0; kc < 2; ++kc) gatherB(Wm2, 64, 128, kc*32 + quad*8, (nb1 + i*4)*16 + nl, B2h[i][kc], B2l[i][kc]);
  short8 B3h[4], B3l[4];
  #pragma unroll
  for (int kc = 0; kc < 4; ++kc) gatherB(Wm3, 128, 64,  kc*32 + quad*8, nb1*16 + nl, B3h[kc], B3l[kc]);
  short8 B4h[2], B4l[2];                  // tileA: cols nb1*16+nl
  #pragma unroll
  for (int kc = 0; kc < 2; ++kc) gatherB(Wm4, 64, 65, kc*32 + quad*8, nb1*16 + nl, B4h[kc], B4l[kc]);
  // gate fragment: lanes 0..7 broadcast col 0 (gate logit), lanes 8..15 broadcast col 64.
  // Every wave computes the gate itself -> no gates[] LDS round-trip, no extra barrier.
  const int gcol = (nl < 8) ? 0 : 64;
  short8 Bgh[2], Bgl[2];
  #pragma unroll
  for (int kc = 0; kc < 2; ++kc) gatherB(Wm4, 64, 65, kc*32 + quad*8, gcol, Bgh[kc], Bgl[kc]);

  const float bi1  = bm1[nb1*16 + nl];
  const float bi2a = bm2[nb1*16 + nl], bi2b = bm2[(nb1+4)*16 + nl];
  const float bi3  = bm3[nb1*16 + nl];
  const float bi4a = bm4[nb1*16 + nl];
  const float big  = bm4[gcol];
  __syncthreads();   // zeros visible before staging writes

  const int ntiles = (E + 63) >> 6;
  const int stride = gridDim.x;
  int t = blockIdx.x;

  // ---- prologue: stage tile t into buffer 0 ----
  if (t < ntiles){
    #pragma unroll
    for (int r2 = 0; r2 < 2; ++r2){
      int row = slot*2 + r2;
      int e = (t << 6) + row;
      int ec = e < E ? e : 0;
      int s = src[ec], d = dst[ec];
      f32x4 v0 = *(const f32x4*)(nf + (size_t)s*64 + nl*4);
      f32x4 v1 = *(const f32x4*)(nf + (size_t)d*64 + nl*4);
      sstore4(Xh, Xl, row*XS + nl*4,      v0);
      sstore4(Xh, Xl, row*XS + 64 + nl*4, v1);
      if (nl < 4){
        f32x4 v2 = *(const f32x4*)(ef + (size_t)ec*16 + nl*4);
        sstore4(Xh, Xl, row*XS + 128 + nl*4, v2);
      }
      if (nl == 5) dstI[row] = (e < E) ? d : -1;
    }
  }
  __syncthreads();

  int p = 0;
  for (; t < ntiles; t += stride, p ^= 1){
    const int tn = t + stride;
    const bool havn = tn < ntiles;
    const short* xh  = Xh  + p*XPL;
    const short* xl  = Xl  + p*XPL;
    short*       h1h = H1h + p*H1PL;
    short*       h1l = H1l + p*H1PL;

    // ---- phase A: issue next-tile gathers into regs (latency hides under L1) ----
    f32x4 ps[2], pd[2], pe[2]; int pid[2];
    if (havn){
      #pragma unroll
      for (int r2 = 0; r2 < 2; ++r2){
        int row = slot*2 + r2;
        int e = (tn << 6) + row;
        int ec = e < E ? e : 0;
        int s = src[ec], d = dst[ec];
        ps[r2] = *(const f32x4*)(nf + (size_t)s*64 + nl*4);
        pd[r2] = *(const f32x4*)(nf + (size_t)d*64 + nl*4);
        if (nl < 4) pe[r2] = *(const f32x4*)(ef + (size_t)ec*16 + nl*4);
        pid[r2] = (e < E) ? d : -1;
      }
    }

    // ---- L1: K=160 (144 real, pad zeroed), X[p] -> H1[p] ----
    {
      f32x4 a1[2] = {{bi1,bi1,bi1,bi1},{bi1,bi1,bi1,bi1}};
      #pragma unroll
      for (int kc = 0; kc < 5; ++kc)
        #pragma unroll
        for (int mb = 0; mb < 2; ++mb){
          int ro = (m1*32 + mb*16 + nl)*XS + kc*32 + quad*8;
          short8 ah = *(const short8*)(xh + ro);
          short8 al = *(const short8*)(xl + ro);
          a1[mb] = mfma3(ah, al, B1h[kc], B1l[kc], a1[mb]);
        }
      #pragma unroll
      for (int mb = 0; mb < 2; ++mb)
        #pragma unroll
        for (int r = 0; r < 4; ++r)
          sstore1(h1h, h1l, (m1*32 + mb*16 + quad*4 + r)*H1S + nb1*16 + nl, lrelu(a1[mb][r]));
    }
    __syncthreads();   // b: also drains prev-tile atomics + our prefetch loads (both in flight during L1)

    // ---- phase C: write staged tile tn into X[p^1] (read-free buffer); L2: H1[p] -> H2 ----
    if (havn){
      short* sxh = Xh + (p^1)*XPL;
      short* sxl = Xl + (p^1)*XPL;
      #pragma unroll
      for (int r2 = 0; r2 < 2; ++r2){
        int row = slot*2 + r2;
        sstore4(sxh, sxl, row*XS + nl*4,      ps[r2]);
        sstore4(sxh, sxl, row*XS + 64 + nl*4, pd[r2]);
        if (nl < 4) sstore4(sxh, sxl, row*XS + 128 + nl*4, pe[r2]);
        if (nl == 5) dstI[(p^1)*64 + row] = pid[r2];
      }
    }
    {
      f32x4 a2a[2] = {{bi2a,bi2a,bi2a,bi2a},{bi2a,bi2a,bi2a,bi2a}};
      f32x4 a2b[2] = {{bi2b,bi2b,bi2b,bi2b},{bi2b,bi2b,bi2b,bi2b}};
      #pragma unroll
      for (int kc = 0; kc < 2; ++kc)
        #pragma unroll
        for (int mb = 0; mb < 2; ++mb){
          int ro = (m1*32 + mb*16 + nl)*H1S + kc*32 + quad*8;
          short8 ah = *(const short8*)(h1h + ro);
          short8 al = *(const short8*)(h1l + ro);
          a2a[mb] = mfma3(ah, al, B2h[0][kc], B2l[0][kc], a2a[mb]);
          a2b[mb] = mfma3(ah, al, B2h[1][kc], B2l[1][kc], a2b[mb]);
        }
      #pragma unroll
      for (int mb = 0; mb < 2; ++mb)
        #pragma unroll
        for (int r = 0; r < 4; ++r){
          int row = m1*32 + mb*16 + quad*4 + r;
          sstore1(H2h, H2l, row*H2S + nb1*16 + nl,     lrelu(a2a[mb][r]));
          sstore1(H2h, H2l, row*H2S + (nb1+4)*16 + nl, lrelu(a2b[mb][r]));
        }
    }
    __syncthreads();   // d

    // ---- L3: K=128, H2 -> H1[p] (L2 reads done at d) ----
    {
      f32x4 a3[2] = {{bi3,bi3,bi3,bi3},{bi3,bi3,bi3,bi3}};
      #pragma unroll
      for (int kc = 0; kc < 4; ++kc)
        #pragma unroll
        for (int mb = 0; mb < 2; ++mb){
          int ro = (m1*32 + mb*16 + nl)*H2S + kc*32 + quad*8;
          short8 ah = *(const short8*)(H2h + ro);
          short8 al = *(const short8*)(H2l + ro);
          a3[mb] = mfma3(ah, al, B3h[kc], B3l[kc], a3[mb]);
        }
      #pragma unroll
      for (int mb = 0; mb < 2; ++mb)
        #pragma unroll
        for (int r = 0; r < 4; ++r)
          sstore1(h1h, h1l, (m1*32 + mb*16 + quad*4 + r)*H1S + nb1*16 + nl, lrelu(a3[mb][r]));
    }
    __syncthreads();   // f

    // ---- L4: K=64, tileA + gate/col64 broadcast frags; scatter (fire-and-forget atomics) ----
    // No tail barrier: next L1 writes H1[p^1] (parity dbuf) and reads X[p^1] (written before d).
    {
      f32x4 a4[2] = {{bi4a,bi4a,bi4a,bi4a},{bi4a,bi4a,bi4a,bi4a}};
      f32x4 ag[2] = {{big,big,big,big},{big,big,big,big}};
      #pragma unroll
      for (int kc = 0; kc < 2; ++kc)
        #pragma unroll
        for (int mb = 0; mb < 2; ++mb){
          int ro = (m1*32 + mb*16 + nl)*H1S + kc*32 + quad*8;
          short8 ah = *(const short8*)(h1h + ro);
          short8 al = *(const short8*)(h1l + ro);
          a4[mb] = mfma3(ah, al, B4h[kc], B4l[kc], a4[mb]);
          ag[mb] = mfma3(ah, al, Bgh[kc], Bgl[kc], ag[mb]);
        }
      const int n = nb1*16 + nl;
      #pragma unroll
      for (int mb = 0; mb < 2; ++mb)
        #pragma unroll
        for (int r = 0; r < 4; ++r){
          int row = m1*32 + mb*16 + quad*4 + r;
          float glog = __shfl(ag[mb][r], lane & 0x30);   // lane nl==0 of this quad holds col-0 logit
          float g = 1.f/(1.f + __expf(-glog));
          int d = dstI[p*64 + row];
          if (d >= 0){
            float v = a4[mb][r] * g;
            if (n >= 1 && n <= 32)  atomicAdd(nf1 + (size_t)d*32 + (n-1), v);
            else if (n >= 33)       atomicMaxF(nf2 + (size_t)d*32 + (n-33), v);
            if (nb1 == 0 && nl == 8)                      // lanes 8..15 hold col-64 output
              atomicMaxF(nf2 + (size_t)d*32 + 31, ag[mb][r] * g);
          }
        }
    }
  }
}

__device__ void zero_f(float* p, int n){
  for (int i = threadIdx.x; i < n; i += blockDim.x) p[i] = 0.f;
}

#define B1S 68    // h-buffer stride: 68%32=4 -> 2-way; 272B %16=0
#define C0S 132   // node buf0 stride: 132%32=4 -> 2-way; 528B %16=0

// RNE split A-chunk (8 f32 from LDS row) -> hi/lo bf16 fragments (node kernel path)
__device__ __forceinline__ void splitA(const float* arow, int k0, short8& hi, short8& lo){
  f32x4 x0 = *(const f32x4*)(arow + k0);
  f32x4 x1 = *(const f32x4*)(arow + k0 + 4);
  #pragma unroll
  for (int j = 0; j < 4; ++j){
    HL a = split1(x0[j]); hi[j]   = a.hi; lo[j]   = a.lo;
    HL b = split1(x1[j]); hi[4+j] = b.hi; lo[4+j] = b.lo;
  }
}

// -------- node kernel: 32 nodes per block-tile, 8 waves (unchanged; ~8% of runtime) --------
__global__ __launch_bounds__(512, 2) void node_mfma(
    const float* __restrict__ nf,
    const float* __restrict__ nf1, const float* __restrict__ nf2,
    const float* __restrict__ Wr1, const float* __restrict__ br1,
    const float* __restrict__ Wr2, const float* __restrict__ br2,
    const float* __restrict__ Wr3, const float* __restrict__ br3,
    const float* __restrict__ Wr4, const float* __restrict__ br4,
    float* __restrict__ out, int N)
{
  __shared__ float buf0[32*C0S];
  __shared__ float buf1[32*B1S];

  zero_f(buf0, 32*C0S);
  zero_f(buf1, 32*B1S);

  const int lane = threadIdx.x & 63, wv = threadIdx.x >> 6;
  const int nl = lane & 15, quad = lane >> 4;
  const int m = wv >> 2, nb = wv & 3;

  short8 B1h[4], B1l[4];
  #pragma unroll
  for (int kc = 0; kc < 4; ++kc) gatherB(Wr1, 128, 64,  kc*32 + quad*8, nb*16 + nl, B1h[kc], B1l[kc]);
  short8 B2h[2][2], B2l[2][2];
  #pragma unroll
  for (int i = 0; i < 2; ++i)
    #pragma unroll
    for (int kc = 0; kc < 2; ++kc) gatherB(Wr2, 64, 128, kc*32 + quad*8, (nb + i*4)*16 + nl, B2h[i][kc], B2l[i][kc]);
  short8 B3h[4], B3l[4];
  #pragma unroll
  for (int kc = 0; kc < 4; ++kc) gatherB(Wr3, 128, 64,  kc*32 + quad*8, nb*16 + nl, B3h[kc], B3l[kc]);
  short8 B4h[2], B4l[2];
  #pragma unroll
  for (int kc = 0; kc < 2; ++kc) gatherB(Wr4, 64, 64,   kc*32 + quad*8, nb*16 + nl, B4h[kc], B4l[kc]);

  const float bi1  = br1[nb*16 + nl];
  const float bi2a = br2[nb*16 + nl], bi2b = br2[(nb+4)*16 + nl];
  const float bi3  = br3[nb*16 + nl];
  const float bi4  = br4[nb*16 + nl];
  __syncthreads();

  const int ntiles = (N + 31) >> 5;
  for (int t = blockIdx.x; t < ntiles; t += gridDim.x){
    const int base = t << 5;
    {
      int row = wv*4 + quad;
      int n = base + row;
      int nc = n < N ? n : 0;
      *(f32x4*)(buf0 + row*C0S + nl*4) = *(const f32x4*)(nf + (size_t)nc*64 + nl*4);
      if (nl < 8){
        *(f32x4*)(buf0 + row*C0S + 64 + nl*4) = *(const f32x4*)(nf1 + (size_t)nc*32 + nl*4);
      } else {
        f32x4 v = *(const f32x4*)(nf2 + (size_t)nc*32 + (nl-8)*4);
        #pragma unroll
        for (int j = 0; j < 4; ++j) if (!(v[j] >= -3.0e38f)) v[j] = 0.f;  // -inf/NaN -> 0
        *(f32x4*)(buf0 + row*C0S + 96 + (nl-8)*4) = v;
      }
    }
    __syncthreads();

    f32x4 a1 = {bi1, bi1, bi1, bi1};
    {
      const float* arow = buf0 + (m*16 + nl)*C0S;
      #pragma unroll
      for (int kc = 0; kc < 4; ++kc){
        short8 ah, al; splitA(arow, kc*32 + quad*8, ah, al);
        a1 = mfma3(ah, al, B1h[kc], B1l[kc], a1);
      }
    }
    #pragma unroll
    for (int r = 0; r < 4; ++r)
      buf1[(m*16 + quad*4 + r)*B1S + nb*16 + nl] = lrelu(a1[r]);
    __syncthreads();

    f32x4 a2a = {bi2a, bi2a, bi2a, bi2a}, a2b = {bi2b, bi2b, bi2b, bi2b};
    {
      const float* arow = buf1 + (m*16 + nl)*B1S;
      #pragma unroll
      for (int kc = 0; kc < 2; ++kc){
        short8 ah, al; splitA(arow, kc*32 + quad*8, ah, al);
        a2a = mfma3(ah, al, B2h[0][kc], B2l[0][kc], a2a);
        a2b = mfma3(ah, al, B2h[1][kc], B2l[1][kc], a2b);
      }
    }
    #pragma unroll
    for (int r = 0; r < 4; ++r){
      buf0[(m*16 + quad*4 + r)*C0S + nb*16 + nl]     = lrelu(a2a[r]);
      buf0[(m*16 + quad*4 + r)*C0S + (nb+4)*16 + nl] = lrelu(a2b[r]);
    }
    __syncthreads();

    f32x4 a3 = {bi3, bi3, bi3, bi3};
    {
      const float* arow = buf0 + (m*16 + nl)*C0S;
      #pragma unroll
      for (int kc = 0; kc < 4; ++kc){
        short8 ah, al; splitA(arow, kc*32 + quad*8, ah, al);
        a3 = mfma3(ah, al, B3h[kc], B3l[kc], a3);
      }
    }
    #pragma unroll
    for (int r = 0; r < 4; ++r)
      buf1[(m*16 + quad*4 + r)*B1S + nb*16 + nl] = lrelu(a3[r]);
    __syncthreads();

    f32x4 a4 = {bi4, bi4, bi4, bi4};
    {
      const float* arow = buf1 + (m*16 + nl)*B1S;
      #pragma unroll
      for (int kc = 0; kc < 2; ++kc){
        short8 ah, al; splitA(arow, kc*32 + quad*8, ah, al);
        a4 = mfma3(ah, al, B4h[kc], B4l[kc], a4);
      }
    }
    #pragma unroll
    for (int r = 0; r < 4; ++r){
      int n = base + m*16 + quad*4 + r;
      if (n < N) out[(size_t)n*64 + nb*16 + nl] = a4[r];
    }
  }
}

extern "C" void kernel_launch(void* const* d_in, const int* in_sizes, int n_in,
                              void* d_out, int out_size, void* d_ws, size_t ws_size,
                              hipStream_t stream) {
  const float* nf  = (const float*)d_in[0];
  const float* ef  = (const float*)d_in[1];
  const int*   src = (const int*)d_in[2];
  const int*   dst = (const int*)d_in[3];

  const int N = in_sizes[0] / 64;
  const int E = in_sizes[2];

  float* nf1 = (float*)d_ws;               // [N,32] segment-sum
  float* nf2 = nf1 + (size_t)N * 32;       // [N,32] segment-max

  static bool attr_set = false;
  if (!attr_set){
    hipFuncSetAttribute((const void*)edge_mfma,
                        hipFuncAttributeMaxDynamicSharedMemorySize, LDS_BYTES);
    attr_set = true;
  }

  init_ws<<<2048, 256, 0, stream>>>(nf1, nf2, N * 32);

  edge_mfma<<<512, 512, LDS_BYTES, stream>>>(
      nf, ef, src, dst,
      (const float*)d_in[4],  (const float*)d_in[5],  (const float*)d_in[6],  (const float*)d_in[7],
      (const float*)d_in[8],  (const float*)d_in[9],  (const float*)d_in[10], (const float*)d_in[11],
      nf1, nf2, E);

  node_mfma<<<512, 512, 0, stream>>>(
      nf, nf1, nf2,
      (const float*)d_in[12], (const float*)d_in[13], (const float*)d_in[14], (const float*)d_in[15],
      (const float*)d_in[16], (const float*)d_in[17], (const float*)d_in[18], (const float*)d_in[19],
      (float*)d_out, N);
}

// Round 2
// 1155.019 us; speedup vs baseline: 1.9915x; 1.9915x over previous
//
#include <hip/hip_runtime.h>

typedef unsigned int u32;
typedef __attribute__((ext_vector_type(8))) short short8;
typedef __attribute__((ext_vector_type(4))) short short4v;
typedef __attribute__((ext_vector_type(4))) float f32x4;

__device__ __forceinline__ float lrelu(float x){ return x > 0.f ? x : 0.2f*x; }

// float atomic max via sign-split (dest init -inf)
__device__ __forceinline__ void atomicMaxF(float* a, float v){
  if (__float_as_int(v) >= 0) atomicMax((int*)a, __float_as_int(v));
  else                        atomicMin((u32*)a, __float_as_uint(v));
}

__global__ void init_ws(float* __restrict__ nf1, float* __restrict__ nf2, int n32){
  int i = blockIdx.x*blockDim.x + threadIdx.x;
  int st = gridDim.x*blockDim.x;
  for (; i < n32; i += st){ nf1[i] = 0.f; nf2[i] = -__builtin_inff(); }
}

// RNE split: x = bf16(hi) + bf16(lo) + O(2^-18 x).
struct HL { short hi, lo; };
__device__ __forceinline__ HL split1(float x){
  u32 u = __float_as_uint(x);
  u32 r = u + 0x7FFFu + ((u >> 16) & 1u);
  float l = x - __uint_as_float(r & 0xFFFF0000u);
  HL o; o.hi = (short)(r >> 16); o.lo = (short)(__float_as_uint(l) >> 16);
  return o;
}

// one-time gather of a B fragment (W row-major [K][Nout], f32) with zero-fill OOB
__device__ __forceinline__ void gatherB(const float* __restrict__ W, int K, int Nout,
                                        int kbase, int n, short8& hi, short8& lo){
  #pragma unroll
  for (int j = 0; j < 8; ++j){
    int k = kbase + j;
    float w = (k < K && n < Nout) ? W[(size_t)k * Nout + n] : 0.f;
    HL s = split1(w); hi[j] = s.hi; lo[j] = s.lo;
  }
}

// 3-product accurate bf16 MFMA: D += Ah*Bh + Al*Bh + Ah*Bl
__device__ __forceinline__ f32x4 mfma3(short8 ah, short8 al, short8 bh, short8 bl, f32x4 c){
  c = __builtin_amdgcn_mfma_f32_16x16x32_bf16(ah, bh, c, 0, 0, 0);
  c = __builtin_amdgcn_mfma_f32_16x16x32_bf16(al, bh, c, 0, 0, 0);
  c = __builtin_amdgcn_mfma_f32_16x16x32_bf16(ah, bl, c, 0, 0, 0);
  return c;
}

// pre-split stores: split once at producer, consumers ds_read_b128 hi/lo planes directly
__device__ __forceinline__ void sstore1(short* hp, short* lp, int idx, float x){
  HL s = split1(x); hp[idx] = s.hi; lp[idx] = s.lo;
}
__device__ __forceinline__ void sstore4(short* hp, short* lp, int idx, f32x4 v){
  short4v h, l;
  #pragma unroll
  for (int j = 0; j < 4; ++j){ HL s = split1(v[j]); h[j] = s.hi; l[j] = s.lo; }
  *(short4v*)(hp + idx) = h;
  *(short4v*)(lp + idx) = l;
}

// ---- edge kernel LDS geometry (all strides in shorts), single-buffered ----
// stride/4 mod 8 != 0 -> <=2-way bank groups (free) for b128 row reads;
// strides are multiples of 8 shorts so rows stay 16B-aligned for ds_read_b128.
#define XS   168            // X rows: 144 real cols + zero pad to K=160 (L1 reads kc=4)
#define H1S  72             // 64-col buffers
#define H2S  136            // 128-col buffer
// short offsets
#define OFF_XL   10752      // Xh @0 (64*168=10752 shorts)
#define OFF_H1H  21504
#define OFF_H1L  26112      // 64*72=4608
#define OFF_H2H  30720
#define OFF_H2L  39424      // 64*136=8704
#define OFF_DST  48128      // int dstI[2][64] parity
#define LDS_SHORTS 48384
#define LDS_BYTES  (LDS_SHORTS*2)   // 96768 B -> 1 block/CU

// -------- edge kernel: 64 edges per block-tile, 8 waves, weights in regs, 4 barriers/tile ------
// MLP_msg 144->64->128->64->65; gate=sigmoid(col0); cols1..32 *g -> sum, 33..64 *g -> max
__global__ __launch_bounds__(512, 2) void edge_mfma(
    const float* __restrict__ nf, const float* __restrict__ ef,
    const int* __restrict__ src, const int* __restrict__ dst,
    const float* __restrict__ Wm1, const float* __restrict__ bm1,
    const float* __restrict__ Wm2, const float* __restrict__ bm2,
    const float* __restrict__ Wm3, const float* __restrict__ bm3,
    const float* __restrict__ Wm4, const float* __restrict__ bm4,
    float* __restrict__ nf1, float* __restrict__ nf2, int E)
{
  extern __shared__ short smem[];
  short* Xh  = smem;
  short* Xl  = smem + OFF_XL;
  short* H1h = smem + OFF_H1H;
  short* H1l = smem + OFF_H1L;
  short* H2h = smem + OFF_H2H;
  short* H2l = smem + OFF_H2L;
  int*  dstI = (int*)(smem + OFF_DST);

  // zero all LDS once: X pad cols 144..159 must stay 0 for the kc=4 MFMA (never rewritten);
  // uninit LDS can hold NaN and 0*NaN = NaN in MFMA.
  {
    float* z = (float*)smem;
    for (int i = threadIdx.x; i < LDS_SHORTS/2; i += blockDim.x) z[i] = 0.f;
  }

  const int lane = threadIdx.x & 63, wv = threadIdx.x >> 6;
  const int nl = lane & 15, quad = lane >> 4;
  const int m1 = wv >> 2, nb1 = wv & 3;   // (m-half, n-block)
  const int slot = wv*4 + quad;           // 0..31, stages rows slot*2, slot*2+1

  // ---- loop-invariant B fragments (hi/lo bf16) in registers ----
  short8 B1h[5], B1l[5];
  #pragma unroll
  for (int kc = 0; kc < 5; ++kc) gatherB(Wm1, 144, 64,  kc*32 + quad*8, nb1*16 + nl, B1h[kc], B1l[kc]);
  short8 B2h[2][2], B2l[2][2];
  #pragma unroll
  for (int i = 0; i < 2; ++i)
    #pragma unroll
    for (int kc = 0; kc < 2; ++kc) gatherB(Wm2, 64, 128, kc*32 + quad*8, (nb1 + i*4)*16 + nl, B2h[i][kc], B2l[i][kc]);
  short8 B3h[4], B3l[4];
  #pragma unroll
  for (int kc = 0; kc < 4; ++kc) gatherB(Wm3, 128, 64,  kc*32 + quad*8, nb1*16 + nl, B3h[kc], B3l[kc]);
  short8 B4h[2], B4l[2];                  // tileA: cols nb1*16+nl
  #pragma unroll
  for (int kc = 0; kc < 2; ++kc) gatherB(Wm4, 64, 65, kc*32 + quad*8, nb1*16 + nl, B4h[kc], B4l[kc]);
  // gate fragment: lanes 0..7 broadcast col 0 (gate logit), lanes 8..15 broadcast col 64.
  // Every wave computes the gate itself -> no gates[] LDS round-trip, no extra barrier.
  const int gcol = (nl < 8) ? 0 : 64;
  short8 Bgh[2], Bgl[2];
  #pragma unroll
  for (int kc = 0; kc < 2; ++kc) gatherB(Wm4, 64, 65, kc*32 + quad*8, gcol, Bgh[kc], Bgl[kc]);

  const float bi1  = bm1[nb1*16 + nl];
  const float bi2a = bm2[nb1*16 + nl], bi2b = bm2[(nb1+4)*16 + nl];
  const float bi3  = bm3[nb1*16 + nl];
  const float bi4a = bm4[nb1*16 + nl];
  const float big  = bm4[gcol];
  __syncthreads();   // zeros visible before staging writes

  const int ntiles = (E + 63) >> 6;
  int pp = 0;
  for (int t = blockIdx.x; t < ntiles; t += gridDim.x, pp ^= 1){
    // ---- stage X = [nf[src]|nf[dst]|ef], split once to hi/lo planes ----
    // Safe vs stragglers in L4(t-1): they read only H1 (protected by bar A: every wave
    // passes L4 before staging) and dstI (parity-buffered).
    #pragma unroll
    for (int r2 = 0; r2 < 2; ++r2){
      int row = slot*2 + r2;
      int e = (t << 6) + row;
      int ec = e < E ? e : 0;
      int s = src[ec], d = dst[ec];
      f32x4 v0 = *(const f32x4*)(nf + (size_t)s*64 + nl*4);
      f32x4 v1 = *(const f32x4*)(nf + (size_t)d*64 + nl*4);
      sstore4(Xh, Xl, row*XS + nl*4,      v0);
      sstore4(Xh, Xl, row*XS + 64 + nl*4, v1);
      if (nl < 4){
        f32x4 v2 = *(const f32x4*)(ef + (size_t)ec*16 + nl*4);
        sstore4(Xh, Xl, row*XS + 128 + nl*4, v2);
      }
      if (nl == 5) dstI[pp*64 + row] = (e < E) ? d : -1;
    }
    __syncthreads();   // A: X visible; all waves past L4(t-1) so H1 reuse below is safe

    // ---- L1: K=160 (144 real, pad zeroed), X -> H1 ----
    {
      f32x4 a1[2] = {{bi1,bi1,bi1,bi1},{bi1,bi1,bi1,bi1}};
      #pragma unroll
      for (int kc = 0; kc < 5; ++kc)
        #pragma unroll
        for (int mb = 0; mb < 2; ++mb){
          int ro = (m1*32 + mb*16 + nl)*XS + kc*32 + quad*8;
          short8 ah = *(const short8*)(Xh + ro);
          short8 al = *(const short8*)(Xl + ro);
          a1[mb] = mfma3(ah, al, B1h[kc], B1l[kc], a1[mb]);
        }
      #pragma unroll
      for (int mb = 0; mb < 2; ++mb)
        #pragma unroll
        for (int r = 0; r < 4; ++r)
          sstore1(H1h, H1l, (m1*32 + mb*16 + quad*4 + r)*H1S + nb1*16 + nl, lrelu(a1[mb][r]));
    }
    __syncthreads();   // B

    // ---- L2: K=64, dual n-block, H1 -> H2 ----
    {
      f32x4 a2a[2] = {{bi2a,bi2a,bi2a,bi2a},{bi2a,bi2a,bi2a,bi2a}};
      f32x4 a2b[2] = {{bi2b,bi2b,bi2b,bi2b},{bi2b,bi2b,bi2b,bi2b}};
      #pragma unroll
      for (int kc = 0; kc < 2; ++kc)
        #pragma unroll
        for (int mb = 0; mb < 2; ++mb){
          int ro = (m1*32 + mb*16 + nl)*H1S + kc*32 + quad*8;
          short8 ah = *(const short8*)(H1h + ro);
          short8 al = *(const short8*)(H1l + ro);
          a2a[mb] = mfma3(ah, al, B2h[0][kc], B2l[0][kc], a2a[mb]);
          a2b[mb] = mfma3(ah, al, B2h[1][kc], B2l[1][kc], a2b[mb]);
        }
      #pragma unroll
      for (int mb = 0; mb < 2; ++mb)
        #pragma unroll
        for (int r = 0; r < 4; ++r){
          int row = m1*32 + mb*16 + quad*4 + r;
          sstore1(H2h, H2l, row*H2S + nb1*16 + nl,     lrelu(a2a[mb][r]));
          sstore1(H2h, H2l, row*H2S + (nb1+4)*16 + nl, lrelu(a2b[mb][r]));
        }
    }
    __syncthreads();   // C

    // ---- L3: K=128, H2 -> H1 (all L2 reads of H1 completed at C) ----
    {
      f32x4 a3[2] = {{bi3,bi3,bi3,bi3},{bi3,bi3,bi3,bi3}};
      #pragma unroll
      for (int kc = 0; kc < 4; ++kc)
        #pragma unroll
        for (int mb = 0; mb < 2; ++mb){
          int ro = (m1*32 + mb*16 + nl)*H2S + kc*32 + quad*8;
          short8 ah = *(const short8*)(H2h + ro);
          short8 al = *(const short8*)(H2l + ro);
          a3[mb] = mfma3(ah, al, B3h[kc], B3l[kc], a3[mb]);
        }
      #pragma unroll
      for (int mb = 0; mb < 2; ++mb)
        #pragma unroll
        for (int r = 0; r < 4; ++r)
          sstore1(H1h, H1l, (m1*32 + mb*16 + quad*4 + r)*H1S + nb1*16 + nl, lrelu(a3[mb][r]));
    }
    __syncthreads();   // D

    // ---- L4: K=64, tileA + gate/col64 broadcast frags; scatter (fire-and-forget atomics) ----
    {
      f32x4 a4[2] = {{bi4a,bi4a,bi4a,bi4a},{bi4a,bi4a,bi4a,bi4a}};
      f32x4 ag[2] = {{big,big,big,big},{big,big,big,big}};
      #pragma unroll
      for (int kc = 0; kc < 2; ++kc)
        #pragma unroll
        for (int mb = 0; mb < 2; ++mb){
          int ro = (m1*32 + mb*16 + nl)*H1S + kc*32 + quad*8;
          short8 ah = *(const short8*)(H1h + ro);
          short8 al = *(const short8*)(H1l + ro);
          a4[mb] = mfma3(ah, al, B4h[kc], B4l[kc], a4[mb]);
          ag[mb] = mfma3(ah, al, Bgh[kc], Bgl[kc], ag[mb]);
        }
      const int n = nb1*16 + nl;
      #pragma unroll
      for (int mb = 0; mb < 2; ++mb)
        #pragma unroll
        for (int r = 0; r < 4; ++r){
          int row = m1*32 + mb*16 + quad*4 + r;
          float glog = __shfl(ag[mb][r], lane & 0x30);   // lane nl==0 of this quad holds col-0 logit
          float g = 1.f/(1.f + __expf(-glog));
          int d = dstI[pp*64 + row];
          if (d >= 0){
            float v = a4[mb][r] * g;
            if (n >= 1 && n <= 32)  atomicAdd(nf1 + (size_t)d*32 + (n-1), v);
            else if (n >= 33)       atomicMaxF(nf2 + (size_t)d*32 + (n-33), v);
            if (nb1 == 0 && nl == 8)                      // lanes 8..15 hold col-64 output
              atomicMaxF(nf2 + (size_t)d*32 + 31, ag[mb][r] * g);
          }
        }
    }
    // no tail barrier: next stage writes X (last read before bar B) and dstI[pp^1]
  }
}

__device__ void zero_f(float* p, int n){
  for (int i = threadIdx.x; i < n; i += blockDim.x) p[i] = 0.f;
}

#define B1S 68    // h-buffer stride: 68%32=4 -> 2-way; 272B %16=0
#define C0S 132   // node buf0 stride: 132%32=4 -> 2-way; 528B %16=0

// RNE split A-chunk (8 f32 from LDS row) -> hi/lo bf16 fragments (node kernel path)
__device__ __forceinline__ void splitA(const float* arow, int k0, short8& hi, short8& lo){
  f32x4 x0 = *(const f32x4*)(arow + k0);
  f32x4 x1 = *(const f32x4*)(arow + k0 + 4);
  #pragma unroll
  for (int j = 0; j < 4; ++j){
    HL a = split1(x0[j]); hi[j]   = a.hi; lo[j]   = a.lo;
    HL b = split1(x1[j]); hi[4+j] = b.hi; lo[4+j] = b.lo;
  }
}

// -------- node kernel: 32 nodes per block-tile, 8 waves (unchanged; ~8% of runtime) --------
__global__ __launch_bounds__(512, 2) void node_mfma(
    const float* __restrict__ nf,
    const float* __restrict__ nf1, const float* __restrict__ nf2,
    const float* __restrict__ Wr1, const float* __restrict__ br1,
    const float* __restrict__ Wr2, const float* __restrict__ br2,
    const float* __restrict__ Wr3, const float* __restrict__ br3,
    const float* __restrict__ Wr4, const float* __restrict__ br4,
    float* __restrict__ out, int N)
{
  __shared__ float buf0[32*C0S];
  __shared__ float buf1[32*B1S];

  zero_f(buf0, 32*C0S);
  zero_f(buf1, 32*B1S);

  const int lane = threadIdx.x & 63, wv = threadIdx.x >> 6;
  const int nl = lane & 15, quad = lane >> 4;
  const int m = wv >> 2, nb = wv & 3;

  short8 B1h[4], B1l[4];
  #pragma unroll
  for (int kc = 0; kc < 4; ++kc) gatherB(Wr1, 128, 64,  kc*32 + quad*8, nb*16 + nl, B1h[kc], B1l[kc]);
  short8 B2h[2][2], B2l[2][2];
  #pragma unroll
  for (int i = 0; i < 2; ++i)
    #pragma unroll
    for (int kc = 0; kc < 2; ++kc) gatherB(Wr2, 64, 128, kc*32 + quad*8, (nb + i*4)*16 + nl, B2h[i][kc], B2l[i][kc]);
  short8 B3h[4], B3l[4];
  #pragma unroll
  for (int kc = 0; kc < 4; ++kc) gatherB(Wr3, 128, 64,  kc*32 + quad*8, nb*16 + nl, B3h[kc], B3l[kc]);
  short8 B4h[2], B4l[2];
  #pragma unroll
  for (int kc = 0; kc < 2; ++kc) gatherB(Wr4, 64, 64,   kc*32 + quad*8, nb*16 + nl, B4h[kc], B4l[kc]);

  const float bi1  = br1[nb*16 + nl];
  const float bi2a = br2[nb*16 + nl], bi2b = br2[(nb+4)*16 + nl];
  const float bi3  = br3[nb*16 + nl];
  const float bi4  = br4[nb*16 + nl];
  __syncthreads();

  const int ntiles = (N + 31) >> 5;
  for (int t = blockIdx.x; t < ntiles; t += gridDim.x){
    const int base = t << 5;
    {
      int row = wv*4 + quad;
      int n = base + row;
      int nc = n < N ? n : 0;
      *(f32x4*)(buf0 + row*C0S + nl*4) = *(const f32x4*)(nf + (size_t)nc*64 + nl*4);
      if (nl < 8){
        *(f32x4*)(buf0 + row*C0S + 64 + nl*4) = *(const f32x4*)(nf1 + (size_t)nc*32 + nl*4);
      } else {
        f32x4 v = *(const f32x4*)(nf2 + (size_t)nc*32 + (nl-8)*4);
        #pragma unroll
        for (int j = 0; j < 4; ++j) if (!(v[j] >= -3.0e38f)) v[j] = 0.f;  // -inf/NaN -> 0
        *(f32x4*)(buf0 + row*C0S + 96 + (nl-8)*4) = v;
      }
    }
    __syncthreads();

    f32x4 a1 = {bi1, bi1, bi1, bi1};
    {
      const float* arow = buf0 + (m*16 + nl)*C0S;
      #pragma unroll
      for (int kc = 0; kc < 4; ++kc){
        short8 ah, al; splitA(arow, kc*32 + quad*8, ah, al);
        a1 = mfma3(ah, al, B1h[kc], B1l[kc], a1);
      }
    }
    #pragma unroll
    for (int r = 0; r < 4; ++r)
      buf1[(m*16 + quad*4 + r)*B1S + nb*16 + nl] = lrelu(a1[r]);
    __syncthreads();

    f32x4 a2a = {bi2a, bi2a, bi2a, bi2a}, a2b = {bi2b, bi2b, bi2b, bi2b};
    {
      const float* arow = buf1 + (m*16 + nl)*B1S;
      #pragma unroll
      for (int kc = 0; kc < 2; ++kc){
        short8 ah, al; splitA(arow, kc*32 + quad*8, ah, al);
        a2a = mfma3(ah, al, B2h[0][kc], B2l[0][kc], a2a);
        a2b = mfma3(ah, al, B2h[1][kc], B2l[1][kc], a2b);
      }
    }
    #pragma unroll
    for (int r = 0; r < 4; ++r){
      buf0[(m*16 + quad*4 + r)*C0S + nb*16 + nl]     = lrelu(a2a[r]);
      buf0[(m*16 + quad*4 + r)*C0S + (nb+4)*16 + nl] = lrelu(a2b[r]);
    }
    __syncthreads();

    f32x4 a3 = {bi3, bi3, bi3, bi3};
    {
      const float* arow = buf0 + (m*16 + nl)*C0S;
      #pragma unroll
      for (int kc = 0; kc < 4; ++kc){
        short8 ah, al; splitA(arow, kc*32 + quad*8, ah, al);
        a3 = mfma3(ah, al, B3h[kc], B3l[kc], a3);
      }
    }
    #pragma unroll
    for (int r = 0; r < 4; ++r)
      buf1[(m*16 + quad*4 + r)*B1S + nb*16 + nl] = lrelu(a3[r]);
    __syncthreads();

    f32x4 a4 = {bi4, bi4, bi4, bi4};
    {
      const float* arow = buf1 + (m*16 + nl)*B1S;
      #pragma unroll
      for (int kc = 0; kc < 2; ++kc){
        short8 ah, al; splitA(arow, kc*32 + quad*8, ah, al);
        a4 = mfma3(ah, al, B4h[kc], B4l[kc], a4);
      }
    }
    #pragma unroll
    for (int r = 0; r < 4; ++r){
      int n = base + m*16 + quad*4 + r;
      if (n < N) out[(size_t)n*64 + nb*16 + nl] = a4[r];
    }
  }
}

extern "C" void kernel_launch(void* const* d_in, const int* in_sizes, int n_in,
                              void* d_out, int out_size, void* d_ws, size_t ws_size,
                              hipStream_t stream) {
  const float* nf  = (const float*)d_in[0];
  const float* ef  = (const float*)d_in[1];
  const int*   src = (const int*)d_in[2];
  const int*   dst = (const int*)d_in[3];

  const int N = in_sizes[0] / 64;
  const int E = in_sizes[2];

  float* nf1 = (float*)d_ws;               // [N,32] segment-sum
  float* nf2 = nf1 + (size_t)N * 32;       // [N,32] segment-max

  static bool attr_set = false;
  if (!attr_set){
    hipFuncSetAttribute((const void*)edge_mfma,
                        hipFuncAttributeMaxDynamicSharedMemorySize, LDS_BYTES);
    attr_set = true;
  }

  init_ws<<<2048, 256, 0, stream>>>(nf1, nf2, N * 32);

  edge_mfma<<<512, 512, LDS_BYTES, stream>>>(
      nf, ef, src, dst,
      (const float*)d_in[4],  (const float*)d_in[5],  (const float*)d_in[6],  (const float*)d_in[7],
      (const float*)d_in[8],  (const float*)d_in[9],  (const float*)d_in[10], (const float*)d_in[11],
      nf1, nf2, E);

  node_mfma<<<512, 512, 0, stream>>>(
      nf, nf1, nf2,
      (const float*)d_in[12], (const float*)d_in[13], (const float*)d_in[14], (const float*)d_in[15],
      (const float*)d_in[16], (const float*)d_in[17], (const float*)d_in[18], (const float*)d_in[19],
      (float*)d_out, N);
}